// Round 4
// baseline (141.533 us; speedup 1.0000x reference)
//
#include <hip/hip_runtime.h>
#include <hip/hip_bf16.h>
#include <math.h>

// Problem constants
#define MM 12544   // 64 * 196 patches
#define KK 768     // 16*16*3
#define NN 768     // embedding dim
// Fully-fused LDS-free GEMM: BM=64, BN=384, 4 waves 1x4 in N (wave: 64x96).
// A is im2col'd INSIDE the GEMM: each lane's A-fragment (row=l&15,
// k=(l>>4)*8..+8) is 8 contiguous 32B-aligned floats in the image ->
// 2x global_load_dwordx4 straight to VGPRs + in-register bf16 convert.
// No apack round-trip, no LDS, no barriers: loads pipeline freely with
// compiler-counted vmcnt; sched_barrier pins the convert AFTER the MFMA
// cluster so the vmcnt wait drains late.
// B comes pre-packed bf16 fragment-major (wpack, 1.18 MB, L2-resident).
#define BM 64
#define BN 384
#define NKS 24             // KK / 32 k-steps
#define MT 196             // MM/BM
#define NT 2               // NN/BN
#define NBLK (MT * NT)     // 392 = 8 * 49 -> clean XCD swizzle, no tail

#define W_CHUNKS (48 * NKS * 64)   // c16-cols x ks x lanes, 16B each

typedef __bf16 v8bf __attribute__((ext_vector_type(8)));
typedef float  v4f  __attribute__((ext_vector_type(4)));

// ---------------------------------------------------------------------------
// W pack: transpose W into fragment-lane-major bf16 chunks.
// chunk id: (ks*48 + c16)*64 + lane ; lane l holds
//   W[ks*32 + (l>>4)*8 .. +8][c16*16 + (l&15)]
// Writes perfectly coalesced (chunk addr = tid*16B).
// ---------------------------------------------------------------------------
__global__ __launch_bounds__(256) void wpack_kernel(const float* __restrict__ w,
                                                    __hip_bfloat16* __restrict__ wpack) {
    int tid  = blockIdx.x * 256 + threadIdx.x;   // 0 .. 73727
    int lane = tid & 63;
    int c16  = (tid >> 6) % 48;
    int ks   = tid / (64 * 48);
    int n    = c16 * 16 + (lane & 15);
    int k0   = ks * 32 + (lane >> 4) * 8;
    union { __hip_bfloat16 h[8]; uint4 u; } o;
#pragma unroll
    for (int j = 0; j < 8; j++) o.h[j] = __float2bfloat16(w[(size_t)(k0 + j) * NN + n]);
    ((uint4*)wpack)[tid] = o.u;
}

// Fast GELU: 0.5x(1+tanh(0.79788456(x+0.044715x^3))) = x * E/(E+1), E=e^{2t}.
// v_exp + v_rcp; max deviation from exact erf-GELU ~3e-3 << 0.103 threshold.
__device__ __forceinline__ float gelu_fast(float x) {
    float t2 = 1.5957691216057308f * x * (1.0f + 0.044715f * x * x);  // 2t
    float e  = __expf(t2);
    float r  = __builtin_amdgcn_rcpf(e + 1.0f);
    return x - x * r;   // x*(1 - 1/(E+1)) = x*E/(E+1)
}

// ---------------------------------------------------------------------------
// Fused im2col + LDS-free MFMA GEMM + bias + fast GELU.
// ---------------------------------------------------------------------------
__global__ __launch_bounds__(256, 2) void gemm_fused(const float* __restrict__ img,
                                                     const __hip_bfloat16* __restrict__ wpack,
                                                     const float* __restrict__ bias,
                                                     float* __restrict__ out) {
    // Bijective XCD swizzle: NBLK=392=8*49; hardware h -> xcd=h&7 gets a
    // contiguous run of 49 logical ids (nt-pairs of ~24.5 mt share one L2).
    const int h  = blockIdx.x;
    const int u  = (h & 7) * 49 + (h >> 3);
    const int mt = u >> 1;
    const int nt = u & 1;

    const int tid  = threadIdx.x;
    const int lane = tid & 63;
    const int wave = tid >> 6;
    const int l_lo = lane & 15;   // row (A) / col (B,C)
    const int l_hi = lane >> 4;   // 8-k group within 32

    // ---- A im2col bases: float index of patch base, per mi ----
    int aoff[4];
#pragma unroll
    for (int mi = 0; mi < 4; mi++) {
        int m  = mt * 64 + mi * 16 + l_lo;
        int b  = m / 196, pm = m - b * 196;
        int pr = pm / 14, pc = pm - pr * 14;
        aoff[mi] = ((b * 224 + pr * 16) * 224 + pc * 16) * 3;
    }
    // k0 = ks*32 + l_hi*8 ; period-3 in ks: i = k0/48, rem = k0%48,
    // rowoff = i*672 + rem ; every 3 ks add 2 image rows = 1344 floats.
    int rowoff[3];
#pragma unroll
    for (int s = 0; s < 3; s++) {
        int k0 = s * 32 + l_hi * 8;       // <= 88
        int i  = (k0 >= 48) ? 1 : 0;
        rowoff[s] = i * 672 + (k0 - i * 48);
    }

    // B chunk index (16B units): (ks*48 + nt*24 + wave*6 + ni)*64 + lane
    const int bbase = (nt * 24 + wave * 6) * 64 + lane;
    const uint4* wp = (const uint4*)wpack;

    v4f acc[4][6];
    const v4f vzero = {0.f, 0.f, 0.f, 0.f};
#pragma unroll
    for (int a = 0; a < 4; a++)
#pragma unroll
        for (int c = 0; c < 6; c++) acc[a][c] = vzero;

    v8bf   aR[2][4];
    v8bf   bR[2][6];
    float4 fA[4][2];

#define LOADA(ks_)                                                            \
    {   _Pragma("unroll")                                                     \
        for (int mi = 0; mi < 4; mi++) {                                      \
            const float* p = img + aoff[mi] + rowoff[(ks_) % 3] + ((ks_) / 3) * 1344; \
            fA[mi][0] = *(const float4*)p;                                    \
            fA[mi][1] = *(const float4*)(p + 4);                              \
        }  }

#define LOADB(ks_, d)                                                         \
    {   _Pragma("unroll")                                                     \
        for (int ni = 0; ni < 6; ni++)                                        \
            bR[d][ni] = *(const v8bf*)&wp[bbase + (ks_) * 3072 + ni * 64];  }

#define CVTA(d)                                                               \
    {   _Pragma("unroll")                                                     \
        for (int mi = 0; mi < 4; mi++) {                                      \
            union { __hip_bfloat16 hh[8]; v8bf v; } t;                        \
            t.hh[0] = __float2bfloat16(fA[mi][0].x);                          \
            t.hh[1] = __float2bfloat16(fA[mi][0].y);                          \
            t.hh[2] = __float2bfloat16(fA[mi][0].z);                          \
            t.hh[3] = __float2bfloat16(fA[mi][0].w);                          \
            t.hh[4] = __float2bfloat16(fA[mi][1].x);                          \
            t.hh[5] = __float2bfloat16(fA[mi][1].y);                          \
            t.hh[6] = __float2bfloat16(fA[mi][1].z);                          \
            t.hh[7] = __float2bfloat16(fA[mi][1].w);                          \
            aR[d][mi] = t.v;                                                  \
        }  }

#define DOMFMA(d)                                                             \
    {   __builtin_amdgcn_s_setprio(1);                                        \
        _Pragma("unroll")                                                     \
        for (int mi = 0; mi < 4; mi++)                                        \
            _Pragma("unroll")                                                 \
            for (int ni = 0; ni < 6; ni++)                                    \
                acc[mi][ni] = __builtin_amdgcn_mfma_f32_16x16x32_bf16(        \
                    aR[d][mi], bR[d][ni], acc[mi][ni], 0, 0, 0);              \
        __builtin_amdgcn_s_setprio(0);  }

    // ---- prologue: ks = 0 ----
    LOADA(0);
    LOADB(0, 0);
    CVTA(0);

    // ---- main loop: issue loads(ks+1) -> MFMA(ks) -> convert(ks+1) ----
#pragma unroll
    for (int ks = 0; ks < NKS; ks++) {
        const int cur = ks & 1;          // literal after full unroll
        const int nxt = cur ^ 1;
        if (ks + 1 < NKS) {
            LOADA(ks + 1);               // f32 image loads, in flight across MFMA
            LOADB(ks + 1, nxt);          // bf16 fragment loads
        }
        DOMFMA(cur);
        __builtin_amdgcn_sched_barrier(0);   // pin cvt (+ its vmcnt wait) after MFMA
        if (ks + 1 < NKS) CVTA(nxt);
    }

    // ---- epilogue: bias + fast GELU, coalesced fp32 stores ----
#pragma unroll
    for (int ni = 0; ni < 6; ni++) {
        int n    = nt * BN + wave * 96 + ni * 16 + l_lo;
        float bv = bias[n];
#pragma unroll
        for (int mi = 0; mi < 4; mi++) {
            int rowb = mt * 64 + mi * 16 + l_hi * 4;
            float* po = out + (size_t)rowb * NN + n;
#pragma unroll
            for (int rg = 0; rg < 4; rg++) {
                float x = acc[mi][ni][rg] + bv;
                po[(size_t)rg * NN] = gelu_fast(x);
            }
        }
    }
#undef LOADA
#undef LOADB
#undef CVTA
#undef DOMFMA
}

extern "C" void kernel_launch(void* const* d_in, const int* in_sizes, int n_in,
                              void* d_out, int out_size, void* d_ws, size_t ws_size,
                              hipStream_t stream) {
    const float* img   = (const float*)d_in[0];   // [64,224,224,3]
    const float* wproj = (const float*)d_in[1];   // [768,768]
    const float* bias  = (const float*)d_in[2];   // [768]
    float* out = (float*)d_out;                   // [64,196,768]

    __hip_bfloat16* wpack = (__hip_bfloat16*)d_ws;   // 1,179,648 B

    wpack_kernel<<<dim3(W_CHUNKS / 256), dim3(256), 0, stream>>>(wproj, wpack);
    gemm_fused<<<dim3(NBLK), dim3(256), 0, stream>>>(img, wpack, bias, out);
}

// Round 5
// 117.891 us; speedup vs baseline: 1.2005x; 1.2005x over previous
//
#include <hip/hip_runtime.h>
#include <hip/hip_bf16.h>
#include <math.h>

// Problem constants
#define MM 12544   // 64 * 196 patches
#define KK 768     // 16*16*3
#define NN 768     // embedding dim
// LDS-free GEMM: BM=64, BN=256, 4 waves 1x4 in N (each wave 64x64 output).
// A and B are pre-packed into FRAGMENT-LANE-MAJOR layout: one MFMA fragment
// (16 rows/cols x 32 k, 64 lanes x 16B) = one contiguous 1KB chunk.
// The GEMM loads fragments global->register directly: no LDS, no barriers,
// no forced vmcnt(0) drains. R5: TWO-deep register prefetch -- fragment
// loads for ks+2 are issued after the MFMA cluster of ks, so data is in
// flight across ~2 full MFMA clusters before its vmcnt wait (covers L2
// latency). Register budget ~160 fits the (256,3) cap, so the allocator
// keeps the pipeline (R4's collapse was 176+ demand vs 96-reg acc).
#define BM 64
#define BN 256
#define NKS 24             // KK / 32 k-steps
#define MT 196             // MM/BM
#define NT 3               // NN/BN
#define N64 12             // NN/64 wave-column groups

#define A_BLOCKS (MT * NKS)    // 4704
#define W_BLOCKS (N64 * NKS)   // 288
#define FRAG_BYTES 1024        // 64 lanes x 16B
#define KSTRIDE (4 * FRAG_BYTES)          // per-ks: 4 frags = 4KB
#define PANEL_BYTES (NKS * KSTRIDE)       // 96KB per 64-row/col panel

typedef __bf16 v8bf __attribute__((ext_vector_type(8)));
typedef float  v4f  __attribute__((ext_vector_type(4)));

// ---------------------------------------------------------------------------
// Pack: im2col A and transpose W into fragment-lane-major bf16 chunks.
// A chunk id: ((mt*24 + ks)*4 + mi)*64 + lane ; lane l = (k8=l>>4, row=l&15)
//   holds A[mt*64 + mi*16 + (l&15)][ks*32 + (l>>4)*8 .. +8]
// W chunk id: ((n64*24 + ks)*4 + ni)*64 + lane
//   holds W[ks*32 + (l>>4)*8 .. +8][n64*64 + ni*16 + (l&15)]
// Writes are perfectly coalesced (chunk addr = base + tid*16).
// ---------------------------------------------------------------------------
__global__ __launch_bounds__(256) void pack_kernel(const float* __restrict__ img,
                                                   const float* __restrict__ w,
                                                   __hip_bfloat16* __restrict__ apack,
                                                   __hip_bfloat16* __restrict__ wpack) {
    const int tid  = threadIdx.x;
    const int l    = tid & 63;
    const int fi   = tid >> 6;      // mi or ni (0..3)
    const int l_lo = l & 15;        // row / col within fragment
    const int l_hi = l >> 4;        // 8-k group within 32

    union { __hip_bfloat16 h[8]; uint4 u; } o;

    if (blockIdx.x < A_BLOCKS) {
        const int bid = blockIdx.x;
        const int mt  = bid / NKS;
        const int ks  = bid - mt * NKS;
        const int m   = mt * 64 + fi * 16 + l_lo;   // global patch index
        const int k0  = ks * 32 + l_hi * 8;         // k within 768
        const int b   = m / 196;
        const int pm  = m - b * 196;
        const int pr  = pm / 14;
        const int pc  = pm - pr * 14;
        const int i   = k0 / 48;                    // row within patch
        const int rem = k0 - i * 48;                // 8-aligned, <=40
        const float* src = img + (size_t)(((b * 224 + pr * 16 + i) * 224 + pc * 16) * 3 + rem);
        float4 f0 = *(const float4*)src;            // 16B-aligned (rem mult of 8 floats)
        float4 f1 = *(const float4*)(src + 4);
        o.h[0] = __float2bfloat16(f0.x); o.h[1] = __float2bfloat16(f0.y);
        o.h[2] = __float2bfloat16(f0.z); o.h[3] = __float2bfloat16(f0.w);
        o.h[4] = __float2bfloat16(f1.x); o.h[5] = __float2bfloat16(f1.y);
        o.h[6] = __float2bfloat16(f1.z); o.h[7] = __float2bfloat16(f1.w);
        ((uint4*)apack)[(size_t)((mt * NKS + ks) * 4 + fi) * 64 + l] = o.u;
    } else {
        const int bid = blockIdx.x - A_BLOCKS;
        const int n64 = bid / NKS;
        const int ks  = bid - n64 * NKS;
        const int col = n64 * 64 + fi * 16 + l_lo;
        const int k0  = ks * 32 + l_hi * 8;
        float f[8];
#pragma unroll
        for (int j = 0; j < 8; j++) f[j] = w[(size_t)(k0 + j) * NN + col];
#pragma unroll
        for (int j = 0; j < 8; j++) o.h[j] = __float2bfloat16(f[j]);
        ((uint4*)wpack)[(size_t)((n64 * NKS + ks) * 4 + fi) * 64 + l] = o.u;
    }
}

// Fast GELU: 0.5x(1+tanh(0.79788456(x+0.044715x^3))) = x * E/(E+1), E=e^{2t}.
// v_exp + v_rcp; max deviation from exact erf-GELU ~3e-3 << 0.103 threshold.
__device__ __forceinline__ float gelu_fast(float x) {
    float t2 = 1.5957691216057308f * x * (1.0f + 0.044715f * x * x);  // 2t
    float e  = __expf(t2);
    float r  = __builtin_amdgcn_rcpf(e + 1.0f);
    return x - x * r;   // x*(1 - 1/(E+1)) = x*E/(E+1)
}

// ---------------------------------------------------------------------------
// LDS-free MFMA GEMM + bias + fast GELU, 2-deep register pipeline.
// 64x256 tile, 4 waves 1x4 in N. A-frags 4x-duplicated across waves -> L1
// hits; B-frags wave-private. XCD chunked swizzle (bijective for 588):
// the 3 nt-blocks of one mt share an XCD's L2 (A-panels + B fit in 4MB).
// ---------------------------------------------------------------------------
__global__ __launch_bounds__(256, 3) void gemm_reg(const __hip_bfloat16* __restrict__ apack,
                                                   const __hip_bfloat16* __restrict__ wpack,
                                                   const float* __restrict__ bias,
                                                   float* __restrict__ out) {
    const int h   = blockIdx.x;
    const int xcd = h & 7;
    const int jj  = h >> 3;
    const int u   = (xcd < 4 ? xcd * 74 : 296 + (xcd - 4) * 73) + jj;
    const int nt  = u % 3;
    const int mt  = u / 3;

    const int tid  = threadIdx.x;
    const int lane = tid & 63;
    const int wave = tid >> 6;
    const int col  = lane & 15;
    const int quad = lane >> 4;

    const char* pA = (const char*)apack + (size_t)mt * PANEL_BYTES + lane * 16;
    const char* pB = (const char*)wpack + (size_t)(nt * 4 + wave) * PANEL_BYTES + lane * 16;

    v4f acc[4][4];
    const v4f vzero = {0.f, 0.f, 0.f, 0.f};
#pragma unroll
    for (int a = 0; a < 4; a++)
#pragma unroll
        for (int c = 0; c < 4; c++) acc[a][c] = vzero;

    v8bf aR[2][4], bR[2][4];
    // ---- prologue: preload ks = 0 (buf0) and ks = 1 (buf1) ----
#pragma unroll
    for (int mi = 0; mi < 4; mi++) {
        aR[0][mi] = *(const v8bf*)(pA + mi * FRAG_BYTES);
        aR[1][mi] = *(const v8bf*)(pA + KSTRIDE + mi * FRAG_BYTES);
    }
#pragma unroll
    for (int ni = 0; ni < 4; ni++) {
        bR[0][ni] = *(const v8bf*)(pB + ni * FRAG_BYTES);
        bR[1][ni] = *(const v8bf*)(pB + KSTRIDE + ni * FRAG_BYTES);
    }

    // ---- main loop: MFMA(ks) then issue loads for ks+2 into buf[ks&1].
    // Loads sit in flight across ~2 MFMA clusters before their vmcnt wait.
#pragma unroll
    for (int ks = 0; ks < NKS; ks++) {
        const int cur = ks & 1;          // literal after full unroll
        __builtin_amdgcn_s_setprio(1);
#pragma unroll
        for (int mi = 0; mi < 4; mi++)
#pragma unroll
            for (int ni = 0; ni < 4; ni++)
                acc[mi][ni] = __builtin_amdgcn_mfma_f32_16x16x32_bf16(
                    aR[cur][mi], bR[cur][ni], acc[mi][ni], 0, 0, 0);
        __builtin_amdgcn_s_setprio(0);
        if (ks + 2 < NKS) {
            const char* qA = pA + (size_t)(ks + 2) * KSTRIDE;
            const char* qB = pB + (size_t)(ks + 2) * KSTRIDE;
#pragma unroll
            for (int mi = 0; mi < 4; mi++)
                aR[cur][mi] = *(const v8bf*)(qA + mi * FRAG_BYTES);
#pragma unroll
            for (int ni = 0; ni < 4; ni++)
                bR[cur][ni] = *(const v8bf*)(qB + ni * FRAG_BYTES);
        }
    }

    // ---- epilogue: bias + fast GELU, coalesced fp32 stores ----
#pragma unroll
    for (int ni = 0; ni < 4; ni++) {
        int n    = nt * BN + wave * 64 + ni * 16 + col;
        float bv = bias[n];
#pragma unroll
        for (int mi = 0; mi < 4; mi++) {
            int rowb = mt * BM + mi * 16 + quad * 4;
            float* po = out + (size_t)rowb * NN + n;
#pragma unroll
            for (int rg = 0; rg < 4; rg++) {
                float x = acc[mi][ni][rg] + bv;
                po[(size_t)rg * NN] = gelu_fast(x);
            }
        }
    }
}

extern "C" void kernel_launch(void* const* d_in, const int* in_sizes, int n_in,
                              void* d_out, int out_size, void* d_ws, size_t ws_size,
                              hipStream_t stream) {
    const float* img   = (const float*)d_in[0];   // [64,224,224,3]
    const float* wproj = (const float*)d_in[1];   // [768,768]
    const float* bias  = (const float*)d_in[2];   // [768]
    float* out = (float*)d_out;                   // [64,196,768]

    __hip_bfloat16* apack = (__hip_bfloat16*)d_ws;                        // 19,267,584 B
    __hip_bfloat16* wpack = (__hip_bfloat16*)((char*)d_ws + (size_t)MM * KK * 2);
    // total ws need: 20,447,232 B

    pack_kernel<<<dim3(A_BLOCKS + W_BLOCKS), dim3(256), 0, stream>>>(
        img, wproj, apack, wpack);
    gemm_reg<<<dim3(MT * NT), dim3(256), 0, stream>>>(apack, wpack, bias, out);
}